// Round 9
// baseline (83.432 us; speedup 1.0000x reference)
//
#include <hip/hip_runtime.h>

#define Bq 2
#define Nq 1024
#define Cq 128
#define Eq 64
#define Kq 20
#define BN (Bq * Nq)
#define BNK (BN * Kq)
#define NEGF (-3.0e38f)
#define REP_A 16
#define REP_B 16
#define REP_C 8
#define REP_D 8

#define DPP_F(x, ctrl) __int_as_float(__builtin_amdgcn_update_dpp( \
    __float_as_int(x), __float_as_int(x), (ctrl), 0xf, 0xf, false))
#define DPP_I(x, ctrl) __builtin_amdgcn_update_dpp((x), (x), (ctrl), 0xf, 0xf, false)
#define RL_F(x, l) __int_as_float(__builtin_amdgcn_readlane(__float_as_int(x), (l)))
#define RL_I(x, l) __builtin_amdgcn_readlane((x), (l))
#define QP_XOR1 0xB1
#define QP_XOR2 0x4E
#define ROR4    0x124
#define ROR8    0x128

// ---------------- proj: unchanged (R8) ----------------
__global__ __launch_bounds__(128) void proj_kernel(
    const float* __restrict__ x, const float* __restrict__ Wl,
    const float* __restrict__ bl, const float* __restrict__ Wr,
    const float* __restrict__ br, const float* __restrict__ att,
    float* __restrict__ xl, float* __restrict__ xrP, float* __restrict__ rdot) {
  const int row = blockIdx.x;
  const int t = threadIdx.x;
  const int e = t & 63;
  const bool left = (t < 64);
  __shared__ float xs[Cq];
  xs[t] = x[(size_t)row * Cq + t];
  __syncthreads();
  const float* __restrict__ W = left ? Wl : Wr;
  float acc = 0.f;
#pragma unroll 8
  for (int c = 0; c < Cq; ++c) acc = fmaf(xs[c], W[c * Eq + e], acc);
  acc += left ? bl[e] : br[e];
  if (left) {
    xl[(size_t)row * Eq + e] = acc;
  } else {
    xrP[((size_t)(e >> 2) * BN + row) * 4 + (e & 3)] = acc;
    float s = acc * att[e];
    s += DPP_F(s, QP_XOR1);
    s += DPP_F(s, QP_XOR2);
    s += DPP_F(s, ROR4);
    s += DPP_F(s, ROR8);
    const float sd = (RL_F(s, 0) + RL_F(s, 16)) + (RL_F(s, 32) + RL_F(s, 48));
    if (e == 0) rdot[row] = sd;
  }
}

// ---------------- V_A: compute-only (real xl/att scalar path, xr synthesized) ----------------
__global__ __launch_bounds__(512) void score_valu(
    const float* __restrict__ xl, const float* __restrict__ att,
    float* __restrict__ junk) {
  const int r0g = blockIdx.x * 4;
  const int jt  = threadIdx.x;
  const float* __restrict__ xlw = xl + (size_t)r0g * Eq;
  const float x0 = (float)jt * 1.0e-6f + 0.5f;      // per-thread VGPR operands
  const float x1 = x0 * 1.0009765625f;
  for (int rep = 0; rep < REP_A; ++rep) {
    float acc[4][2] = {{0.f,0.f},{0.f,0.f},{0.f,0.f},{0.f,0.f}};
#pragma unroll
    for (int ch = 0; ch < 16; ++ch) {
      const float4 a0 = *(const float4*)(xlw + ch * 4);
      const float4 a1 = *(const float4*)(xlw + Eq + ch * 4);
      const float4 a2 = *(const float4*)(xlw + 2 * Eq + ch * 4);
      const float4 a3 = *(const float4*)(xlw + 3 * Eq + ch * 4);
      const float4 at = *(const float4*)(att + ch * 4);
      const float* a0p = (const float*)&a0;
      const float* a1p = (const float*)&a1;
      const float* a2p = (const float*)&a2;
      const float* a3p = (const float*)&a3;
      const float* atp = (const float*)&at;
#pragma unroll
      for (int dd = 0; dd < 4; ++dd) {
        const float a = atp[dd];
        acc[0][0] = fmaf(fabsf(a0p[dd] + x0), a, acc[0][0]);
        acc[0][1] = fmaf(fabsf(a0p[dd] + x1), a, acc[0][1]);
        acc[1][0] = fmaf(fabsf(a1p[dd] + x0), a, acc[1][0]);
        acc[1][1] = fmaf(fabsf(a1p[dd] + x1), a, acc[1][1]);
        acc[2][0] = fmaf(fabsf(a2p[dd] + x0), a, acc[2][0]);
        acc[2][1] = fmaf(fabsf(a2p[dd] + x1), a, acc[2][1]);
        acc[3][0] = fmaf(fabsf(a3p[dd] + x0), a, acc[3][0]);
        acc[3][1] = fmaf(fabsf(a3p[dd] + x1), a, acc[3][1]);
      }
    }
    junk[(size_t)blockIdx.x * 512 + jt] =
        acc[0][0] + acc[0][1] + acc[1][0] + acc[1][1] +
        acc[2][0] + acc[2][1] + acc[3][0] + acc[3][1];
    asm volatile("" ::: "memory");
  }
}

// ---------------- V_B: memory-only (identical xr stream + pipeline, no fma chain) ----------------
__global__ __launch_bounds__(512) void score_mem(
    const float* __restrict__ xrP, float* __restrict__ junk) {
  const int b  = (blockIdx.x * 4) >> 10;
  const int jt = threadIdx.x;
  for (int rep = 0; rep < REP_B; ++rep) {
    const float* __restrict__ vb = xrP + (size_t)(b * Nq + jt) * 4;
    float4 nv0 = *(const float4*)(vb);
    float4 nv1 = *(const float4*)(vb + 512 * 4);
    float4 A = make_float4(0.f, 0.f, 0.f, 0.f);
    float4 Bv = make_float4(0.f, 0.f, 0.f, 0.f);
#pragma unroll
    for (int ch = 0; ch < 16; ++ch) {
      const float4 v0 = nv0, v1 = nv1;
      if (ch < 15) {
        vb += BN * 4;
        nv0 = *(const float4*)(vb);
        nv1 = *(const float4*)(vb + 512 * 4);
      }
      A.x += v0.x; A.y += v0.y; A.z += v0.z; A.w += v0.w;
      Bv.x += v1.x; Bv.y += v1.y; Bv.z += v1.z; Bv.w += v1.w;
    }
    junk[(size_t)blockIdx.x * 512 + jt] =
        A.x + A.y + A.z + A.w + Bv.x + Bv.y + Bv.z + Bv.w;
    asm volatile("" ::: "memory");
  }
}

// ---------------- V_C: full phase-1, 4 rows x 2 j (R8 core as standalone) ----------------
__global__ __launch_bounds__(512) void score_c(
    const float* __restrict__ xl, const float* __restrict__ xrP,
    const float* __restrict__ rdot, const float* __restrict__ att,
    float* __restrict__ alphaG) {
  const int r0g = blockIdx.x * 4;
  const int b   = r0g >> 10;
  const int jt  = threadIdx.x;
  const float* __restrict__ xlw = xl + (size_t)r0g * Eq;
  for (int rep = 0; rep < REP_C; ++rep) {
    const float rd0 = 1.5f * rdot[b * Nq + jt];
    const float rd1 = 1.5f * rdot[b * Nq + jt + 512];
    float acc[4][2];
#pragma unroll
    for (int r = 0; r < 4; ++r) { acc[r][0] = rd0; acc[r][1] = rd1; }
    const float* __restrict__ vb = xrP + (size_t)(b * Nq + jt) * 4;
    float4 nv0 = *(const float4*)(vb);
    float4 nv1 = *(const float4*)(vb + 512 * 4);
    float4 na0 = *(const float4*)(xlw);
    float4 na1 = *(const float4*)(xlw + Eq);
    float4 na2 = *(const float4*)(xlw + 2 * Eq);
    float4 na3 = *(const float4*)(xlw + 3 * Eq);
    float4 nat = *(const float4*)(att);
#pragma unroll
    for (int ch = 0; ch < 16; ++ch) {
      const float4 v0 = nv0, v1 = nv1;
      const float4 a0 = na0, a1 = na1, a2 = na2, a3 = na3, at = nat;
      if (ch < 15) {
        vb += BN * 4;
        nv0 = *(const float4*)(vb);
        nv1 = *(const float4*)(vb + 512 * 4);
        na0 = *(const float4*)(xlw + (ch + 1) * 4);
        na1 = *(const float4*)(xlw + Eq + (ch + 1) * 4);
        na2 = *(const float4*)(xlw + 2 * Eq + (ch + 1) * 4);
        na3 = *(const float4*)(xlw + 3 * Eq + (ch + 1) * 4);
        nat = *(const float4*)(att + (ch + 1) * 4);
      }
      const float* v0p = (const float*)&v0;
      const float* v1p = (const float*)&v1;
      const float* a0p = (const float*)&a0;
      const float* a1p = (const float*)&a1;
      const float* a2p = (const float*)&a2;
      const float* a3p = (const float*)&a3;
      const float* atp = (const float*)&at;
#pragma unroll
      for (int dd = 0; dd < 4; ++dd) {
        const float a = atp[dd];
        const float x0 = v0p[dd], x1 = v1p[dd];
        acc[0][0] = fmaf(fabsf(a0p[dd] + x0), a, acc[0][0]);
        acc[0][1] = fmaf(fabsf(a0p[dd] + x1), a, acc[0][1]);
        acc[1][0] = fmaf(fabsf(a1p[dd] + x0), a, acc[1][0]);
        acc[1][1] = fmaf(fabsf(a1p[dd] + x1), a, acc[1][1]);
        acc[2][0] = fmaf(fabsf(a2p[dd] + x0), a, acc[2][0]);
        acc[2][1] = fmaf(fabsf(a2p[dd] + x1), a, acc[2][1]);
        acc[3][0] = fmaf(fabsf(a3p[dd] + x0), a, acc[3][0]);
        acc[3][1] = fmaf(fabsf(a3p[dd] + x1), a, acc[3][1]);
      }
    }
#pragma unroll
    for (int r = 0; r < 4; ++r) {
      alphaG[(size_t)(r0g + r) * Nq + jt]       = acc[r][0];
      alphaG[(size_t)(r0g + r) * Nq + jt + 512] = acc[r][1];
    }
    asm volatile("" ::: "memory");
  }
}

// ---------------- V_D: full phase-1, 8 rows x 2 j (2x arith intensity) ----------------
__global__ __launch_bounds__(512) void score_d(
    const float* __restrict__ xl, const float* __restrict__ xrP,
    const float* __restrict__ rdot, const float* __restrict__ att,
    float* __restrict__ alphaG) {
  const int r0g = blockIdx.x * 8;
  const int b   = r0g >> 10;
  const int jt  = threadIdx.x;
  const float* __restrict__ xlw = xl + (size_t)r0g * Eq;
  for (int rep = 0; rep < REP_D; ++rep) {
    const float rd0 = 1.5f * rdot[b * Nq + jt];
    const float rd1 = 1.5f * rdot[b * Nq + jt + 512];
    float acc[8][2];
#pragma unroll
    for (int r = 0; r < 8; ++r) { acc[r][0] = rd0; acc[r][1] = rd1; }
    const float* __restrict__ vb = xrP + (size_t)(b * Nq + jt) * 4;
    float4 nv0 = *(const float4*)(vb);
    float4 nv1 = *(const float4*)(vb + 512 * 4);
#pragma unroll
    for (int ch = 0; ch < 16; ++ch) {
      const float4 v0 = nv0, v1 = nv1;
      if (ch < 15) {
        vb += BN * 4;
        nv0 = *(const float4*)(vb);
        nv1 = *(const float4*)(vb + 512 * 4);
      }
      const float4 at = *(const float4*)(att + ch * 4);
      const float* v0p = (const float*)&v0;
      const float* v1p = (const float*)&v1;
      const float* atp = (const float*)&at;
#pragma unroll
      for (int dd = 0; dd < 4; ++dd) {
        const float a = atp[dd];
        const float x0 = v0p[dd], x1 = v1p[dd];
#pragma unroll
        for (int r = 0; r < 8; ++r) {
          const float xld = xlw[r * Eq + ch * 4 + dd];   // uniform -> s_load
          acc[r][0] = fmaf(fabsf(xld + x0), a, acc[r][0]);
          acc[r][1] = fmaf(fabsf(xld + x1), a, acc[r][1]);
        }
      }
    }
#pragma unroll
    for (int r = 0; r < 8; ++r) {
      alphaG[(size_t)(r0g + r) * Nq + jt]       = acc[r][0];
      alphaG[(size_t)(r0g + r) * Nq + jt + 512] = acc[r][1];
    }
    asm volatile("" ::: "memory");
  }
}

// ---------------- topk: wave-per-row, DPP-only (R6-verified) ----------------
__global__ __launch_bounds__(256) void topk_kernel(
    const float* __restrict__ alphaG, float* __restrict__ out) {
  const int row  = blockIdx.x * 4 + (threadIdx.x >> 6);
  const int lane = threadIdx.x & 63;
  const int b    = row >> 10;
  float vals[16];
#pragma unroll
  for (int s = 0; s < 16; ++s) vals[s] = alphaG[(size_t)row * Nq + lane + 64 * s];

  float lv = vals[0];
  int   pk = lane;
#pragma unroll
  for (int s = 1; s < 16; ++s)
    if (vals[s] > lv) { lv = vals[s]; pk = (s << 6) | lane; }

  float m0 = 0.f, ssum = 0.f, myv = 0.f;
  int myi = 0;
#pragma unroll 1
  for (int round = 0; round < Kq; ++round) {
    float m = lv;
    m = fmaxf(m, DPP_F(m, QP_XOR1));
    m = fmaxf(m, DPP_F(m, QP_XOR2));
    m = fmaxf(m, DPP_F(m, ROR4));
    m = fmaxf(m, DPP_F(m, ROR8));
    const float bv = fmaxf(fmaxf(RL_F(m, 0), RL_F(m, 16)),
                           fmaxf(RL_F(m, 32), RL_F(m, 48)));
    int key = (lv == bv) ? pk : 0x7FFFFFFF;
    key = min(key, DPP_I(key, QP_XOR1));
    key = min(key, DPP_I(key, QP_XOR2));
    key = min(key, DPP_I(key, ROR4));
    key = min(key, DPP_I(key, ROR8));
    const int jsel = min(min(RL_I(key, 0), RL_I(key, 16)),
                         min(RL_I(key, 32), RL_I(key, 48)));
    if (round == 0) m0 = bv;
    ssum += __expf(0.4f * (bv - m0));
    if (lane == round) { myv = bv; myi = jsel; }
    if (lane == (jsel & 63)) {
      const int sk = jsel >> 6;
#pragma unroll
      for (int s = 0; s < 16; ++s)
        if (s == sk) vals[s] = NEGF;
      lv = vals[0]; pk = lane;
#pragma unroll
      for (int s = 1; s < 16; ++s)
        if (vals[s] > lv) { lv = vals[s]; pk = (s << 6) | lane; }
    }
  }

  if (lane < Kq) {
    const float p = __expf(0.4f * (myv - m0)) / ssum;
    const int base = row * Kq + lane;
    out[base]            = (float)row;
    out[BNK + base]      = (float)(b * Nq + myi);
    out[2 * BNK + base]  = p;
  }
}

extern "C" void kernel_launch(void* const* d_in, const int* in_sizes, int n_in,
                              void* d_out, int out_size, void* d_ws, size_t ws_size,
                              hipStream_t stream) {
  const float* x   = (const float*)d_in[0];
  const float* Wl  = (const float*)d_in[1];
  const float* bl  = (const float*)d_in[2];
  const float* Wr  = (const float*)d_in[3];
  const float* br  = (const float*)d_in[4];
  const float* att = (const float*)d_in[5];
  float* out = (float*)d_out;

  float* xl     = (float*)d_ws;                    // [B*N, E]
  float* xrP    = xl + (size_t)BN * Eq;            // [16][B*N][4]
  float* rdot   = xrP + (size_t)16 * BN * 4;       // [B*N]
  float* alphaG = rdot + (size_t)BN;               // [B*N, N] = 8 MB
  float* junk   = alphaG + (size_t)BN * Nq;        // diagnostic sink

  proj_kernel<<<BN, 128, 0, stream>>>(x, Wl, bl, Wr, br, att, xl, xrP, rdot);
  score_valu<<<BN / 4, 512, 0, stream>>>(xl, att, junk);
  score_mem<<<BN / 4, 512, 0, stream>>>(xrP, junk);
  score_c<<<BN / 4, 512, 0, stream>>>(xl, xrP, rdot, att, alphaG);
  score_d<<<BN / 8, 512, 0, stream>>>(xl, xrP, rdot, att, alphaG);
  topk_kernel<<<BN / 4, 256, 0, stream>>>(alphaG, out);
}

// Round 10
// 55.444 us; speedup vs baseline: 1.5048x; 1.5048x over previous
//
#include <hip/hip_runtime.h>

#define Bq 2
#define Nq 1024
#define Cq 128
#define Eq 64
#define Kq 20
#define BN (Bq * Nq)
#define BNK (BN * Kq)
#define NEGF (-3.0e38f)

#define DPP_F(x, ctrl) __int_as_float(__builtin_amdgcn_update_dpp( \
    __float_as_int(x), __float_as_int(x), (ctrl), 0xf, 0xf, false))
#define DPP_I(x, ctrl) __builtin_amdgcn_update_dpp((x), (x), (ctrl), 0xf, 0xf, false)
#define RL_F(x, l) __int_as_float(__builtin_amdgcn_readlane(__float_as_int(x), (l)))
#define RL_I(x, l) __builtin_amdgcn_readlane((x), (l))
#define QP_XOR1 0xB1   // quad_perm [1,0,3,2]
#define QP_XOR2 0x4E   // quad_perm [2,3,0,1]
#define ROR4    0x124  // row_ror:4
#define ROR8    0x128  // row_ror:8

// ---------------- proj: x@Wl+bl -> xl ; x@Wr+br -> xrP (plane-major) + rdot ----------------
// grid = B*N, block = 128 (2 waves). Wave 0 -> Wl, wave 1 -> Wr.
__global__ __launch_bounds__(128) void proj_kernel(
    const float* __restrict__ x, const float* __restrict__ Wl,
    const float* __restrict__ bl, const float* __restrict__ Wr,
    const float* __restrict__ br, const float* __restrict__ att,
    float* __restrict__ xl, float* __restrict__ xrP, float* __restrict__ rdot) {
  const int row = blockIdx.x;
  const int t = threadIdx.x;
  const int e = t & 63;
  const bool left = (t < 64);
  __shared__ float xs[Cq];
  xs[t] = x[(size_t)row * Cq + t];
  __syncthreads();
  const float* __restrict__ W = left ? Wl : Wr;
  float acc = 0.f;
#pragma unroll 8
  for (int c = 0; c < Cq; ++c) acc = fmaf(xs[c], W[c * Eq + e], acc);
  acc += left ? bl[e] : br[e];
  if (left) {
    xl[(size_t)row * Eq + e] = acc;
  } else {
    // plane-major: xrP[ch=e>>2][row][c=e&3]
    xrP[((size_t)(e >> 2) * BN + row) * 4 + (e & 3)] = acc;
    float s = acc * att[e];                 // rdot[row] = sum_e xr[row][e]*att[e]
    s += DPP_F(s, QP_XOR1);
    s += DPP_F(s, QP_XOR2);
    s += DPP_F(s, ROR4);
    s += DPP_F(s, ROR8);
    const float sd = (RL_F(s, 0) + RL_F(s, 16)) + (RL_F(s, 32) + RL_F(s, 48));
    if (e == 0) rdot[row] = sd;
  }
}

// ---------------- score: phase-1 standalone (R9 V_C, measured <=4.9us) ----------------
// grid = BN/4 (512 blocks), block = 512. Thread tile: 4 rows x 2 j (j = jt, jt+512).
// alphaS[r][j] = 1.5*rdot[j] + sum_d att[d]*|xl[r][d]+xr[j][d]|  (scaled; topk undoes 0.4)
__global__ __launch_bounds__(512) void score_kernel(
    const float* __restrict__ xl, const float* __restrict__ xrP,
    const float* __restrict__ rdot, const float* __restrict__ att,
    float* __restrict__ alphaG) {
  const int r0g = blockIdx.x * 4;
  const int b   = r0g >> 10;
  const int jt  = threadIdx.x;
  const float* __restrict__ xlw = xl + (size_t)r0g * Eq;   // block-uniform -> s_load

  const float rd0 = 1.5f * rdot[b * Nq + jt];
  const float rd1 = 1.5f * rdot[b * Nq + jt + 512];
  float acc[4][2];
#pragma unroll
  for (int r = 0; r < 4; ++r) { acc[r][0] = rd0; acc[r][1] = rd1; }

  const float* __restrict__ vb = xrP + (size_t)(b * Nq + jt) * 4;
  // prefetch ch=0 (1-ahead software pipeline, controlled VGPR)
  float4 nv0 = *(const float4*)(vb);
  float4 nv1 = *(const float4*)(vb + 512 * 4);
  float4 na0 = *(const float4*)(xlw);
  float4 na1 = *(const float4*)(xlw + Eq);
  float4 na2 = *(const float4*)(xlw + 2 * Eq);
  float4 na3 = *(const float4*)(xlw + 3 * Eq);
  float4 nat = *(const float4*)(att);

#pragma unroll
  for (int ch = 0; ch < 16; ++ch) {
    const float4 v0 = nv0, v1 = nv1;
    const float4 a0 = na0, a1 = na1, a2 = na2, a3 = na3, at = nat;
    if (ch < 15) {                        // issue ch+1 loads before computing ch
      vb += BN * 4;                       // next plane
      nv0 = *(const float4*)(vb);
      nv1 = *(const float4*)(vb + 512 * 4);
      na0 = *(const float4*)(xlw + (ch + 1) * 4);
      na1 = *(const float4*)(xlw + Eq + (ch + 1) * 4);
      na2 = *(const float4*)(xlw + 2 * Eq + (ch + 1) * 4);
      na3 = *(const float4*)(xlw + 3 * Eq + (ch + 1) * 4);
      nat = *(const float4*)(att + (ch + 1) * 4);
    }
    const float* v0p = (const float*)&v0;
    const float* v1p = (const float*)&v1;
    const float* a0p = (const float*)&a0;
    const float* a1p = (const float*)&a1;
    const float* a2p = (const float*)&a2;
    const float* a3p = (const float*)&a3;
    const float* atp = (const float*)&at;
#pragma unroll
    for (int dd = 0; dd < 4; ++dd) {
      const float a = atp[dd];
      const float x0 = v0p[dd], x1 = v1p[dd];
      acc[0][0] = fmaf(fabsf(a0p[dd] + x0), a, acc[0][0]);
      acc[0][1] = fmaf(fabsf(a0p[dd] + x1), a, acc[0][1]);
      acc[1][0] = fmaf(fabsf(a1p[dd] + x0), a, acc[1][0]);
      acc[1][1] = fmaf(fabsf(a1p[dd] + x1), a, acc[1][1]);
      acc[2][0] = fmaf(fabsf(a2p[dd] + x0), a, acc[2][0]);
      acc[2][1] = fmaf(fabsf(a2p[dd] + x1), a, acc[2][1]);
      acc[3][0] = fmaf(fabsf(a3p[dd] + x0), a, acc[3][0]);
      acc[3][1] = fmaf(fabsf(a3p[dd] + x1), a, acc[3][1]);
    }
  }
#pragma unroll
  for (int r = 0; r < 4; ++r) {
    alphaG[(size_t)(r0g + r) * Nq + jt]       = acc[r][0];
    alphaG[(size_t)(r0g + r) * Nq + jt + 512] = acc[r][1];
  }
}

// ---------------- topk: wave-per-row, DPP-only reduces + softmax + outputs ----------------
// grid = BN/4, block = 256 (4 waves).
__global__ __launch_bounds__(256) void topk_kernel(
    const float* __restrict__ alphaG, float* __restrict__ out) {
  const int row  = blockIdx.x * 4 + (threadIdx.x >> 6);
  const int lane = threadIdx.x & 63;
  const int b    = row >> 10;
  float vals[16];
#pragma unroll
  for (int s = 0; s < 16; ++s) vals[s] = alphaG[(size_t)row * Nq + lane + 64 * s];

  float lv = vals[0];
  int   pk = lane;                        // pk = (s<<6)|lane == j
#pragma unroll
  for (int s = 1; s < 16; ++s)
    if (vals[s] > lv) { lv = vals[s]; pk = (s << 6) | lane; }

  float m0 = 0.f, ssum = 0.f, myv = 0.f;
  int myi = 0;
#pragma unroll 1
  for (int round = 0; round < Kq; ++round) {
    float m = lv;
    m = fmaxf(m, DPP_F(m, QP_XOR1));
    m = fmaxf(m, DPP_F(m, QP_XOR2));
    m = fmaxf(m, DPP_F(m, ROR4));
    m = fmaxf(m, DPP_F(m, ROR8));
    const float bv = fmaxf(fmaxf(RL_F(m, 0), RL_F(m, 16)),
                           fmaxf(RL_F(m, 32), RL_F(m, 48)));
    int key = (lv == bv) ? pk : 0x7FFFFFFF;   // min-j tie-break (lax.top_k)
    key = min(key, DPP_I(key, QP_XOR1));
    key = min(key, DPP_I(key, QP_XOR2));
    key = min(key, DPP_I(key, ROR4));
    key = min(key, DPP_I(key, ROR8));
    const int jsel = min(min(RL_I(key, 0), RL_I(key, 16)),
                         min(RL_I(key, 32), RL_I(key, 48)));
    if (round == 0) m0 = bv;
    ssum += __expf(0.4f * (bv - m0));     // undo the /0.4 scaling here
    if (lane == round) { myv = bv; myi = jsel; }
    if (lane == (jsel & 63)) {            // owner knockout + rescan
      const int sk = jsel >> 6;
#pragma unroll
      for (int s = 0; s < 16; ++s)
        if (s == sk) vals[s] = NEGF;
      lv = vals[0]; pk = lane;
#pragma unroll
      for (int s = 1; s < 16; ++s)
        if (vals[s] > lv) { lv = vals[s]; pk = (s << 6) | lane; }
    }
  }

  if (lane < Kq) {
    const float p = __expf(0.4f * (myv - m0)) / ssum;
    const int base = row * Kq + lane;
    out[base]            = (float)row;            // index_i
    out[BNK + base]      = (float)(b * Nq + myi); // index_j
    out[2 * BNK + base]  = p;                     // attention
  }
}

extern "C" void kernel_launch(void* const* d_in, const int* in_sizes, int n_in,
                              void* d_out, int out_size, void* d_ws, size_t ws_size,
                              hipStream_t stream) {
  const float* x   = (const float*)d_in[0];
  const float* Wl  = (const float*)d_in[1];
  const float* bl  = (const float*)d_in[2];
  const float* Wr  = (const float*)d_in[3];
  const float* br  = (const float*)d_in[4];
  const float* att = (const float*)d_in[5];
  float* out = (float*)d_out;

  float* xl     = (float*)d_ws;                    // [B*N, E]
  float* xrP    = xl + (size_t)BN * Eq;            // [16][B*N][4] plane-major
  float* rdot   = xrP + (size_t)16 * BN * 4;       // [B*N]
  float* alphaG = rdot + (size_t)BN;               // [B*N, N] = 8 MB

  proj_kernel<<<BN, 128, 0, stream>>>(x, Wl, bl, Wr, br, att, xl, xrP, rdot);
  score_kernel<<<BN / 4, 512, 0, stream>>>(xl, xrP, rdot, att, alphaG);
  topk_kernel<<<BN / 4, 256, 0, stream>>>(alphaG, out);
}

// Round 11
// 38.778 us; speedup vs baseline: 2.1515x; 1.4298x over previous
//
#include <hip/hip_runtime.h>

#define Bq 2
#define Nq 1024
#define Cq 128
#define Eq 64
#define Kq 20
#define TI 4
#define BN (Bq * Nq)
#define BNK (BN * Kq)
#define NEGF (-3.0e38f)

#define DPP_F(x, ctrl) __int_as_float(__builtin_amdgcn_update_dpp( \
    __float_as_int(x), __float_as_int(x), (ctrl), 0xf, 0xf, false))
#define DPP_I(x, ctrl) __builtin_amdgcn_update_dpp((x), (x), (ctrl), 0xf, 0xf, false)
#define RL_F(x, l) __int_as_float(__builtin_amdgcn_readlane(__float_as_int(x), (l)))
#define RL_I(x, l) __builtin_amdgcn_readlane((x), (l))
#define QP_XOR1 0xB1   // quad_perm [1,0,3,2]
#define QP_XOR2 0x4E   // quad_perm [2,3,0,1]
#define ROR4    0x124  // row_ror:4
#define ROR8    0x128  // row_ror:8

// ---------------- proj: x@Wl+bl -> xl ; x@Wr+br -> xrP (plane-major) + rdot ----------------
// grid = B*N, block = 128 (2 waves). Wave 0 -> Wl, wave 1 -> Wr. (unchanged, ~3us)
__global__ __launch_bounds__(128) void proj_kernel(
    const float* __restrict__ x, const float* __restrict__ Wl,
    const float* __restrict__ bl, const float* __restrict__ Wr,
    const float* __restrict__ br, const float* __restrict__ att,
    float* __restrict__ xl, float* __restrict__ xrP, float* __restrict__ rdot) {
  const int row = blockIdx.x;
  const int t = threadIdx.x;
  const int e = t & 63;
  const bool left = (t < 64);
  __shared__ float xs[Cq];
  xs[t] = x[(size_t)row * Cq + t];
  __syncthreads();
  const float* __restrict__ W = left ? Wl : Wr;
  float acc = 0.f;
#pragma unroll 8
  for (int c = 0; c < Cq; ++c) acc = fmaf(xs[c], W[c * Eq + e], acc);
  acc += left ? bl[e] : br[e];
  if (left) {
    xl[(size_t)row * Eq + e] = acc;
  } else {
    // plane-major: xrP[ch=e>>2][row][c=e&3]
    xrP[((size_t)(e >> 2) * BN + row) * 4 + (e & 3)] = acc;
    float s = acc * att[e];                 // rdot[row] = sum_e xr[row][e]*att[e]
    s += DPP_F(s, QP_XOR1);
    s += DPP_F(s, QP_XOR2);
    s += DPP_F(s, ROR4);
    s += DPP_F(s, ROR8);
    const float sd = (RL_F(s, 0) + RL_F(s, 16)) + (RL_F(s, 32) + RL_F(s, 48));
    if (e == 0) rdot[row] = sd;
  }
}

// ---------------- attn: fused score (V_C core) + top-K, 512 threads, NO SPILLS ----------------
// grid = BN/4 = 512 blocks, block = 512 (8 waves) -> VGPR cap 128, fits ~80-reg pipeline.
// Phase 1: thread tile 4 rows x 2 j (j = jt, jt+512), alpha -> LDS (16 KB).
// Phase 2: waves 0..3 own rows 0..3 (DPP-only top-K).
__global__ __launch_bounds__(512) void attn_kernel(
    const float* __restrict__ xl, const float* __restrict__ xrP,
    const float* __restrict__ rdot, const float* __restrict__ att,
    float* __restrict__ out) {
  const int r0g  = blockIdx.x * TI;
  const int b    = r0g >> 10;
  const int tid  = threadIdx.x;
  const int lane = tid & 63;
  const int wave = tid >> 6;

  __shared__ float alpha[TI][Nq];   // 16 KB

  // ---- phase 1: exactly the R9/R10-measured V_C core, destination = LDS ----
  {
    const int jt = tid;
    const float* __restrict__ xlw = xl + (size_t)r0g * Eq;  // block-uniform -> s_load

    const float rd0 = 1.5f * rdot[b * Nq + jt];
    const float rd1 = 1.5f * rdot[b * Nq + jt + 512];
    float acc[TI][2];
#pragma unroll
    for (int r = 0; r < TI; ++r) { acc[r][0] = rd0; acc[r][1] = rd1; }

    const float* __restrict__ vb = xrP + (size_t)(b * Nq + jt) * 4;
    // 1-ahead software pipeline (prefetch ch=0)
    float4 nv0 = *(const float4*)(vb);
    float4 nv1 = *(const float4*)(vb + 512 * 4);
    float4 na0 = *(const float4*)(xlw);
    float4 na1 = *(const float4*)(xlw + Eq);
    float4 na2 = *(const float4*)(xlw + 2 * Eq);
    float4 na3 = *(const float4*)(xlw + 3 * Eq);
    float4 nat = *(const float4*)(att);

#pragma unroll
    for (int ch = 0; ch < 16; ++ch) {
      const float4 v0 = nv0, v1 = nv1;
      const float4 a0 = na0, a1 = na1, a2 = na2, a3 = na3, at = nat;
      if (ch < 15) {                      // issue ch+1 loads before computing ch
        vb += BN * 4;                     // next plane
        nv0 = *(const float4*)(vb);
        nv1 = *(const float4*)(vb + 512 * 4);
        na0 = *(const float4*)(xlw + (ch + 1) * 4);
        na1 = *(const float4*)(xlw + Eq + (ch + 1) * 4);
        na2 = *(const float4*)(xlw + 2 * Eq + (ch + 1) * 4);
        na3 = *(const float4*)(xlw + 3 * Eq + (ch + 1) * 4);
        nat = *(const float4*)(att + (ch + 1) * 4);
      }
      const float* v0p = (const float*)&v0;
      const float* v1p = (const float*)&v1;
      const float* a0p = (const float*)&a0;
      const float* a1p = (const float*)&a1;
      const float* a2p = (const float*)&a2;
      const float* a3p = (const float*)&a3;
      const float* atp = (const float*)&at;
#pragma unroll
      for (int dd = 0; dd < 4; ++dd) {
        const float a = atp[dd];
        const float x0 = v0p[dd], x1 = v1p[dd];
        acc[0][0] = fmaf(fabsf(a0p[dd] + x0), a, acc[0][0]);
        acc[0][1] = fmaf(fabsf(a0p[dd] + x1), a, acc[0][1]);
        acc[1][0] = fmaf(fabsf(a1p[dd] + x0), a, acc[1][0]);
        acc[1][1] = fmaf(fabsf(a1p[dd] + x1), a, acc[1][1]);
        acc[2][0] = fmaf(fabsf(a2p[dd] + x0), a, acc[2][0]);
        acc[2][1] = fmaf(fabsf(a2p[dd] + x1), a, acc[2][1]);
        acc[3][0] = fmaf(fabsf(a3p[dd] + x0), a, acc[3][0]);
        acc[3][1] = fmaf(fabsf(a3p[dd] + x1), a, acc[3][1]);
      }
    }
#pragma unroll
    for (int r = 0; r < TI; ++r) {
      alpha[r][jt]       = acc[r][0];
      alpha[r][jt + 512] = acc[r][1];
    }
  }
  __syncthreads();

  // ---- phase 2: waves 0..3 = top-K of row `wave`, DPP-only reduces ----
  if (wave < TI) {
    float vals[16];
#pragma unroll
    for (int s = 0; s < 16; ++s) vals[s] = alpha[wave][lane + 64 * s];

    float lv = vals[0];
    int   pk = lane;                      // pk = (s<<6)|lane == j
#pragma unroll
    for (int s = 1; s < 16; ++s)
      if (vals[s] > lv) { lv = vals[s]; pk = (s << 6) | lane; }

    float m0 = 0.f, ssum = 0.f, myv = 0.f;
    int myi = 0;
#pragma unroll 1
    for (int round = 0; round < Kq; ++round) {
      float m = lv;
      m = fmaxf(m, DPP_F(m, QP_XOR1));
      m = fmaxf(m, DPP_F(m, QP_XOR2));
      m = fmaxf(m, DPP_F(m, ROR4));
      m = fmaxf(m, DPP_F(m, ROR8));
      const float bv = fmaxf(fmaxf(RL_F(m, 0), RL_F(m, 16)),
                             fmaxf(RL_F(m, 32), RL_F(m, 48)));
      int key = (lv == bv) ? pk : 0x7FFFFFFF;   // min-j tie-break (lax.top_k)
      key = min(key, DPP_I(key, QP_XOR1));
      key = min(key, DPP_I(key, QP_XOR2));
      key = min(key, DPP_I(key, ROR4));
      key = min(key, DPP_I(key, ROR8));
      const int jsel = min(min(RL_I(key, 0), RL_I(key, 16)),
                           min(RL_I(key, 32), RL_I(key, 48)));
      if (round == 0) m0 = bv;
      ssum += __expf(0.4f * (bv - m0));   // undo the /0.4 scaling here
      if (lane == round) { myv = bv; myi = jsel; }
      if (lane == (jsel & 63)) {          // owner knockout + rescan
        const int sk = jsel >> 6;
#pragma unroll
        for (int s = 0; s < 16; ++s)
          if (s == sk) vals[s] = NEGF;
        lv = vals[0]; pk = lane;
#pragma unroll
        for (int s = 1; s < 16; ++s)
          if (vals[s] > lv) { lv = vals[s]; pk = (s << 6) | lane; }
      }
    }

    if (lane < Kq) {
      const int gi = r0g + wave;
      const float p = __expf(0.4f * (myv - m0)) / ssum;
      const int base = gi * Kq + lane;
      out[base]            = (float)gi;              // index_i
      out[BNK + base]      = (float)(b * Nq + myi);  // index_j
      out[2 * BNK + base]  = p;                      // attention
    }
  }
}

extern "C" void kernel_launch(void* const* d_in, const int* in_sizes, int n_in,
                              void* d_out, int out_size, void* d_ws, size_t ws_size,
                              hipStream_t stream) {
  const float* x   = (const float*)d_in[0];
  const float* Wl  = (const float*)d_in[1];
  const float* bl  = (const float*)d_in[2];
  const float* Wr  = (const float*)d_in[3];
  const float* br  = (const float*)d_in[4];
  const float* att = (const float*)d_in[5];
  float* out = (float*)d_out;

  float* xl   = (float*)d_ws;                    // [B*N, E]
  float* xrP  = xl + (size_t)BN * Eq;            // [16][B*N][4] plane-major
  float* rdot = xrP + (size_t)16 * BN * 4;       // [B*N]

  proj_kernel<<<BN, 128, 0, stream>>>(x, Wl, bl, Wr, br, att, xl, xrP, rdot);
  attn_kernel<<<BN / TI, 512, 0, stream>>>(xl, xrP, rdot, att, out);
}